// Round 2
// baseline (414.713 us; speedup 1.0000x reference)
//
#include <hip/hip_runtime.h>

typedef short short8 __attribute__((ext_vector_type(8)));
typedef float f32x4 __attribute__((ext_vector_type(4)));

#define N_B   4
#define S_LEN 2048
#define EMB   512
#define HD    64
#define NHB   32                      // N_B * HEADS
#define SCALE 0.04419417382415922f    // 1/sqrt(512)

// static device scratch (avoid dependence on ws_size); fully rewritten every call
__device__ unsigned short g_Wqb[64*64];
__device__ unsigned short g_Wkb[64*64];
__device__ unsigned short g_Wvb[64*64];
__device__ unsigned short g_Wob[512*512];
__device__ unsigned short g_Qp[NHB*S_LEN*HD];   // [nh][s][d]
__device__ unsigned short g_Kp[NHB*S_LEN*HD];   // [nh][s][d]
__device__ unsigned short g_Vt[NHB*HD*S_LEN];   // [nh][d][s]  (transposed V)
__device__ unsigned short g_AO[N_B*S_LEN*EMB];  // attention output, bf16

__device__ __forceinline__ unsigned short f2bf(float f) {
  unsigned u = __float_as_uint(f);
  u = u + 0x7fffu + ((u >> 16) & 1u);   // RNE
  return (unsigned short)(u >> 16);
}

// ---------------- k0: weight f32 -> bf16 ----------------
__global__ __launch_bounds__(256) void k0_wconv(const float* __restrict__ Wq,
                                                const float* __restrict__ Wk,
                                                const float* __restrict__ Wv,
                                                const float* __restrict__ Wo) {
  int idx = blockIdx.x * 256 + threadIdx.x;          // 274432 total
  if (idx < 4096)        g_Wqb[idx]         = f2bf(Wq[idx]);
  else if (idx < 8192)   g_Wkb[idx - 4096]  = f2bf(Wk[idx - 4096]);
  else if (idx < 12288)  g_Wvb[idx - 8192]  = f2bf(Wv[idx - 8192]);
  else                   g_Wob[idx - 12288] = f2bf(Wo[idx - 12288]);
}

// ---------------- k1: QKV projections (K=64 GEMM per head) ----------------
// out[row][e] = sum_d X[row][h*64+d] * W[e][d];  V additionally transposed to [d][s]
__global__ __launch_bounds__(256) void k1_proj(const float* __restrict__ q_in,
                                               const float* __restrict__ k_in,
                                               const float* __restrict__ v_in) {
  __shared__ unsigned short VtL[64][72];
  const int tid = threadIdx.x;
  const int w = tid >> 6, lane = tid & 63, g = lane >> 4, c = lane & 15;
  const int s0 = blockIdx.x * 64;
  const int nh = blockIdx.y, n = nh >> 3, h = nh & 7;
  const int which = blockIdx.z;                       // 0=q 1=k 2=v
  const float* src = which == 0 ? q_in : (which == 1 ? k_in : v_in);
  const unsigned short* Wb = which == 0 ? g_Wqb : (which == 1 ? g_Wkb : g_Wvb);

  // A fragments: 16 rows of X (f32 -> bf16 in registers)
  short8 a[2];
  const int arow = s0 + w * 16 + c;
#pragma unroll
  for (int ks = 0; ks < 2; ++ks) {
    const float* ap = src + ((size_t)n * S_LEN + arow) * EMB + h * HD + ks * 32 + g * 8;
    f32x4 x0 = *(const f32x4*)ap;
    f32x4 x1 = *(const f32x4*)(ap + 4);
    short8 t;
    t[0] = (short)f2bf(x0[0]); t[1] = (short)f2bf(x0[1]);
    t[2] = (short)f2bf(x0[2]); t[3] = (short)f2bf(x0[3]);
    t[4] = (short)f2bf(x1[0]); t[5] = (short)f2bf(x1[1]);
    t[6] = (short)f2bf(x1[2]); t[7] = (short)f2bf(x1[3]);
    a[ks] = t;
  }

  f32x4 acc[4];
#pragma unroll
  for (int dt = 0; dt < 4; ++dt) { acc[dt][0]=0.f; acc[dt][1]=0.f; acc[dt][2]=0.f; acc[dt][3]=0.f; }

#pragma unroll
  for (int ks = 0; ks < 2; ++ks)
#pragma unroll
    for (int dt = 0; dt < 4; ++dt) {
      short8 b = *(const short8*)(Wb + (dt * 16 + c) * HD + ks * 32 + g * 8);
      acc[dt] = __builtin_amdgcn_mfma_f32_16x16x32_bf16(a[ks], b, acc[dt], 0, 0, 0);
    }

  if (which < 2) {
    unsigned short* dst = which == 0 ? g_Qp : g_Kp;
#pragma unroll
    for (int dt = 0; dt < 4; ++dt)
#pragma unroll
      for (int r = 0; r < 4; ++r) {
        int srow = s0 + w * 16 + 4 * g + r;
        dst[((size_t)nh * S_LEN + srow) * HD + dt * 16 + c] = f2bf(acc[dt][r]);
      }
  } else {
    // transpose 64x64 tile in LDS, then coalesced store of Vt rows
#pragma unroll
    for (int dt = 0; dt < 4; ++dt)
#pragma unroll
      for (int r = 0; r < 4; ++r)
        VtL[dt * 16 + c][w * 16 + 4 * g + r] = f2bf(acc[dt][r]);
    __syncthreads();
#pragma unroll
    for (int rep = 0; rep < 2; ++rep) {
      int cid = tid + rep * 256;
      int row = cid >> 3, ch = cid & 7;
      short8 v = *(const short8*)(&VtL[row][ch * 8]);
      *(short8*)(g_Vt + ((size_t)nh * HD + row) * S_LEN + s0 + ch * 8) = v;
    }
  }
}

// ---------------- k2: flash attention ----------------
// block: 64 Q-rows (4 waves x 16), loop over 32 KV tiles of 64
__global__ __launch_bounds__(256) void k2_attn(const int* __restrict__ mask) {
  __shared__ unsigned short Kl[64][72];       // [kv][d]
  __shared__ unsigned short Vl[64][72];       // [d][kv]  (from g_Vt)
  __shared__ unsigned short Pl[4][16][72];    // per-wave P tile [q][kv]
  const int tid = threadIdx.x;
  const int w = tid >> 6, lane = tid & 63, g = lane >> 4, c = lane & 15;
  const int q0 = blockIdx.x * 64;
  const int nh = blockIdx.y, n = nh >> 3, h = nh & 7;

  short8 aq[2];
#pragma unroll
  for (int ks = 0; ks < 2; ++ks)
    aq[ks] = *(const short8*)(g_Qp + ((size_t)nh * S_LEN + q0 + w * 16 + c) * HD + ks * 32 + g * 8);

  float m4[4], l4[4];
  f32x4 O4[4];
#pragma unroll
  for (int r = 0; r < 4; ++r) { m4[r] = -1e30f; l4[r] = 0.f; }
#pragma unroll
  for (int dt = 0; dt < 4; ++dt) { O4[dt][0]=0.f; O4[dt][1]=0.f; O4[dt][2]=0.f; O4[dt][3]=0.f; }

  const int* mrow = mask + (size_t)n * S_LEN * S_LEN;

  for (int t = 0; t < 32; ++t) {
    const int kv0 = t * 64;
    if (t) __syncthreads();
    // stage K tile and Vt tile (reg -> LDS, padded rows)
#pragma unroll
    for (int rep = 0; rep < 2; ++rep) {
      int cid = tid + rep * 256;
      int row = cid >> 3, ch = cid & 7;
      *(short8*)(&Kl[row][ch * 8]) =
          *(const short8*)(g_Kp + ((size_t)nh * S_LEN + kv0 + row) * HD + ch * 8);
      *(short8*)(&Vl[row][ch * 8]) =
          *(const short8*)(g_Vt + ((size_t)nh * HD + row) * S_LEN + kv0 + ch * 8);
    }
    __syncthreads();

    // S = Q K^T  (16 q-rows x 64 kv-cols per wave)
    f32x4 sa[4];
#pragma unroll
    for (int ct = 0; ct < 4; ++ct) { sa[ct][0]=0.f; sa[ct][1]=0.f; sa[ct][2]=0.f; sa[ct][3]=0.f; }
#pragma unroll
    for (int ks = 0; ks < 2; ++ks)
#pragma unroll
      for (int ct = 0; ct < 4; ++ct) {
        short8 bk = *(const short8*)(&Kl[ct * 16 + c][g * 8 + ks * 32]);
        sa[ct] = __builtin_amdgcn_mfma_f32_16x16x32_bf16(aq[ks], bk, sa[ct], 0, 0, 0);
      }

    // mask + scale
#pragma unroll
    for (int ct = 0; ct < 4; ++ct)
#pragma unroll
      for (int r = 0; r < 4; ++r) {
        int qr = q0 + w * 16 + 4 * g + r;
        int mk = mrow[(size_t)qr * S_LEN + kv0 + ct * 16 + c];
        sa[ct][r] = mk ? sa[ct][r] * SCALE : -1e30f;
      }

    // online softmax per row (row = 4g+r, cols across 16 lanes x 4 ct)
    float corr[4];
#pragma unroll
    for (int r = 0; r < 4; ++r) {
      float mx = fmaxf(fmaxf(sa[0][r], sa[1][r]), fmaxf(sa[2][r], sa[3][r]));
      mx = fmaxf(mx, __shfl_xor(mx, 1));
      mx = fmaxf(mx, __shfl_xor(mx, 2));
      mx = fmaxf(mx, __shfl_xor(mx, 4));
      mx = fmaxf(mx, __shfl_xor(mx, 8));
      float mn = fmaxf(m4[r], mx);
      corr[r] = __expf(m4[r] - mn);
      m4[r] = mn;
      float ps = 0.f;
#pragma unroll
      for (int ct = 0; ct < 4; ++ct) {
        float p = __expf(sa[ct][r] - mn);   // masked -> exp(-huge)=0
        sa[ct][r] = p;
        ps += p;
      }
      ps += __shfl_xor(ps, 1); ps += __shfl_xor(ps, 2);
      ps += __shfl_xor(ps, 4); ps += __shfl_xor(ps, 8);
      l4[r] = l4[r] * corr[r] + ps;
    }

    // P -> bf16 -> wave-private LDS (becomes PV A-fragment)
#pragma unroll
    for (int ct = 0; ct < 4; ++ct)
#pragma unroll
      for (int r = 0; r < 4; ++r)
        Pl[w][4 * g + r][ct * 16 + c] = f2bf(sa[ct][r]);

    // rescale O
#pragma unroll
    for (int dt = 0; dt < 4; ++dt)
#pragma unroll
      for (int r = 0; r < 4; ++r)
        O4[dt][r] *= corr[r];

    // O += P V
#pragma unroll
    for (int ks = 0; ks < 2; ++ks) {
      short8 pa = *(const short8*)(&Pl[w][c][g * 8 + ks * 32]);
#pragma unroll
      for (int dt = 0; dt < 4; ++dt) {
        short8 bv = *(const short8*)(&Vl[dt * 16 + c][g * 8 + ks * 32]);
        O4[dt] = __builtin_amdgcn_mfma_f32_16x16x32_bf16(pa, bv, O4[dt], 0, 0, 0);
      }
    }
  }

  // epilogue: O / l -> g_AO [n][s][h*64+d] bf16
#pragma unroll
  for (int r = 0; r < 4; ++r) {
    float inv = l4[r] > 0.f ? 1.f / l4[r] : 0.f;
    int qr = q0 + w * 16 + 4 * g + r;
#pragma unroll
    for (int dt = 0; dt < 4; ++dt)
      g_AO[((size_t)n * S_LEN + qr) * EMB + h * HD + dt * 16 + c] = f2bf(O4[dt][r] * inv);
  }
}

// ---------------- k3: output projection (8192x512x512) + bias ----------------
__global__ __launch_bounds__(256) void k3_oproj(const float* __restrict__ bo,
                                                float* __restrict__ out) {
  const int tid = threadIdx.x;
  const int w = tid >> 6, lane = tid & 63, g = lane >> 4, c = lane & 15;
  const int m0 = blockIdx.x * 256 + w * 64;
  const int n0 = blockIdx.y * 64;

  f32x4 acc[4][4];
#pragma unroll
  for (int mf = 0; mf < 4; ++mf)
#pragma unroll
    for (int ct = 0; ct < 4; ++ct) { acc[mf][ct][0]=0.f; acc[mf][ct][1]=0.f; acc[mf][ct][2]=0.f; acc[mf][ct][3]=0.f; }

  for (int ks = 0; ks < 16; ++ks) {
    short8 a[4], b[4];
#pragma unroll
    for (int mf = 0; mf < 4; ++mf)
      a[mf] = *(const short8*)(g_AO + ((size_t)(m0 + mf * 16 + c)) * EMB + ks * 32 + g * 8);
#pragma unroll
    for (int ct = 0; ct < 4; ++ct)
      b[ct] = *(const short8*)(g_Wob + (size_t)(n0 + ct * 16 + c) * EMB + ks * 32 + g * 8);
#pragma unroll
    for (int mf = 0; mf < 4; ++mf)
#pragma unroll
      for (int ct = 0; ct < 4; ++ct)
        acc[mf][ct] = __builtin_amdgcn_mfma_f32_16x16x32_bf16(a[mf], b[ct], acc[mf][ct], 0, 0, 0);
  }

#pragma unroll
  for (int mf = 0; mf < 4; ++mf)
#pragma unroll
    for (int ct = 0; ct < 4; ++ct)
#pragma unroll
      for (int r = 0; r < 4; ++r) {
        int row = m0 + mf * 16 + 4 * g + r;
        int col = n0 + ct * 16 + c;
        out[(size_t)row * EMB + col] = acc[mf][ct][r] + bo[col];
      }
}

extern "C" void kernel_launch(void* const* d_in, const int* in_sizes, int n_in,
                              void* d_out, int out_size, void* d_ws, size_t ws_size,
                              hipStream_t stream) {
  const float* value = (const float*)d_in[0];
  const float* key   = (const float*)d_in[1];
  const float* query = (const float*)d_in[2];
  const int*   mask  = (const int*)d_in[3];
  const float* Wq    = (const float*)d_in[4];
  const float* Wk    = (const float*)d_in[5];
  const float* Wv    = (const float*)d_in[6];
  const float* Wo    = (const float*)d_in[7];
  const float* bo    = (const float*)d_in[8];
  float* out = (float*)d_out;

  k0_wconv<<<1072, 256, 0, stream>>>(Wq, Wk, Wv, Wo);
  k1_proj<<<dim3(32, 32, 3), 256, 0, stream>>>(query, key, value);
  k2_attn<<<dim3(32, 32), 256, 0, stream>>>(mask);
  k3_oproj<<<dim3(32, 8), 256, 0, stream>>>(bo, out);
}

// Round 4
// 326.326 us; speedup vs baseline: 1.2709x; 1.2709x over previous
//
#include <hip/hip_runtime.h>

typedef short short8 __attribute__((ext_vector_type(8)));
typedef float f32x4 __attribute__((ext_vector_type(4)));
typedef unsigned short ushort4v __attribute__((ext_vector_type(4)));
typedef unsigned long long u64;
typedef u64 u64x2 __attribute__((ext_vector_type(2)));

#define N_B   4
#define S_LEN 2048
#define EMB   512
#define HD    64
#define NHB   32                      // N_B * HEADS
#define QSCALE 0.04419417382415922f   // 1/sqrt(512), folded into Wq

// static device scratch; fully rewritten every call
__device__ unsigned short g_Wqb[64*64];
__device__ unsigned short g_Wkb[64*64];
__device__ unsigned short g_Wvb[64*64];
__device__ unsigned short g_Wob[512*512];
__device__ unsigned short g_Qp[NHB*S_LEN*HD];   // [nh][s][d] (pre-scaled by QSCALE)
__device__ unsigned short g_Kp[NHB*S_LEN*HD];   // [nh][s][d]
__device__ unsigned short g_Vt[NHB*HD*S_LEN];   // [nh][d][s]
__device__ unsigned short g_AO[N_B*S_LEN*EMB];  // attention output, bf16
__device__ u64            g_Mb[N_B*32*S_LEN];   // packed mask bits [n][t][q]

__device__ __forceinline__ unsigned short f2bf(float f) {
  unsigned u = __float_as_uint(f);
  u = u + 0x7fffu + ((u >> 16) & 1u);   // RNE
  return (unsigned short)(u >> 16);
}

// ---------------- k0: weight f32 -> bf16 (Wq pre-scaled) ----------------
__global__ __launch_bounds__(256) void k0_wconv(const float* __restrict__ Wq,
                                                const float* __restrict__ Wk,
                                                const float* __restrict__ Wv,
                                                const float* __restrict__ Wo) {
  int idx = blockIdx.x * 256 + threadIdx.x;          // 274432 total
  if (idx < 4096)        g_Wqb[idx]         = f2bf(Wq[idx] * QSCALE);
  else if (idx < 8192)   g_Wkb[idx - 4096]  = f2bf(Wk[idx - 4096]);
  else if (idx < 12288)  g_Wvb[idx - 8192]  = f2bf(Wv[idx - 8192]);
  else                   g_Wob[idx - 12288] = f2bf(Wo[idx - 12288]);
}

// ---------------- k0b: pack mask ints -> bits (one wave per 64 ints) -----
__global__ __launch_bounds__(256) void k0b_mask(const int* __restrict__ mask) {
  int wid = blockIdx.x * 4 + (threadIdx.x >> 6);      // (n*32+t)*2048 + q
  int lane = threadIdx.x & 63;
  int q = wid & 2047;
  int nt = wid >> 11;
  int t = nt & 31, n = nt >> 5;
  int mk = mask[((size_t)(n * 2048 + q) << 11) + t * 64 + lane];
  u64 bits = __ballot(mk != 0);
  if (lane == 0) g_Mb[wid] = bits;
}

// ---------------- k1: QKV projections, swapped operands (C^T) -----------
// C^T[e][s]: A = W rows(e), B = X cols(s). Q/K: packed 8B stores along e.
// V: direct scatter into transposed layout [d][s].
__global__ __launch_bounds__(256) void k1_proj(const float* __restrict__ q_in,
                                               const float* __restrict__ k_in,
                                               const float* __restrict__ v_in) {
  const int tid = threadIdx.x;
  const int w = tid >> 6, lane = tid & 63, g = lane >> 4, c = lane & 15;
  const int s0 = blockIdx.x * 64;
  const int nh = blockIdx.y, n = nh >> 3, h = nh & 7;
  const int which = blockIdx.z;                       // 0=q 1=k 2=v
  const float* src = which == 0 ? q_in : (which == 1 ? k_in : v_in);
  const unsigned short* Wb = which == 0 ? g_Wqb : (which == 1 ? g_Wkb : g_Wvb);

  // B fragments: X rows (col = s = c), f32 -> bf16
  short8 xb[2];
  const int srow = s0 + w * 16 + c;
#pragma unroll
  for (int ks = 0; ks < 2; ++ks) {
    const float* ap = src + ((size_t)n * S_LEN + srow) * EMB + h * HD + ks * 32 + g * 8;
    f32x4 x0 = *(const f32x4*)ap;
    f32x4 x1 = *(const f32x4*)(ap + 4);
    short8 tt;
    tt[0] = (short)f2bf(x0[0]); tt[1] = (short)f2bf(x0[1]);
    tt[2] = (short)f2bf(x0[2]); tt[3] = (short)f2bf(x0[3]);
    tt[4] = (short)f2bf(x1[0]); tt[5] = (short)f2bf(x1[1]);
    tt[6] = (short)f2bf(x1[2]); tt[7] = (short)f2bf(x1[3]);
    xb[ks] = tt;
  }

  f32x4 acc[4];
#pragma unroll
  for (int dt = 0; dt < 4; ++dt) { acc[dt][0]=0.f; acc[dt][1]=0.f; acc[dt][2]=0.f; acc[dt][3]=0.f; }

#pragma unroll
  for (int ks = 0; ks < 2; ++ks)
#pragma unroll
    for (int dt = 0; dt < 4; ++dt) {
      short8 a = *(const short8*)(Wb + (dt * 16 + c) * HD + ks * 32 + g * 8);
      acc[dt] = __builtin_amdgcn_mfma_f32_16x16x32_bf16(a, xb[ks], acc[dt], 0, 0, 0);
    }

  // acc[dt]: e = dt*16 + 4g + r, s = srow
  if (which < 2) {
    unsigned short* dst = which == 0 ? g_Qp : g_Kp;
#pragma unroll
    for (int dt = 0; dt < 4; ++dt) {
      ushort4v u;
      u[0] = f2bf(acc[dt][0]); u[1] = f2bf(acc[dt][1]);
      u[2] = f2bf(acc[dt][2]); u[3] = f2bf(acc[dt][3]);
      *(ushort4v*)(dst + ((size_t)nh * S_LEN + srow) * HD + dt * 16 + 4 * g) = u;
    }
  } else {
#pragma unroll
    for (int dt = 0; dt < 4; ++dt)
#pragma unroll
      for (int r = 0; r < 4; ++r)
        g_Vt[((size_t)nh * HD + dt * 16 + 4 * g + r) * S_LEN + srow] = f2bf(acc[dt][r]);
  }
}

// ---------------- k2: flash attention, pipelined -------------------------
// 8 waves x 16 q-rows = 128 q/block; KV tile 64; dbuf swizzled LDS; bitmask.
__global__ __launch_bounds__(512) void k2_attn() {
  __shared__ unsigned short Kl[2][64][64];   // [buf][kv][d], chunk^=(row&7)
  __shared__ unsigned short Vl[2][64][64];   // [buf][d][kv], chunk^=(row&7)
  __shared__ unsigned short Pl[8][16][64];   // per-wave P [q][kv], swizzled
  const int tid = threadIdx.x;
  const int w = tid >> 6, lane = tid & 63, g = lane >> 4, c = lane & 15;
  const int q0 = blockIdx.x * 128;
  const int nh = blockIdx.y, n = nh >> 3, h = nh & 7;

  // Q fragments (16 rows per wave)
  short8 aq[2];
#pragma unroll
  for (int ks = 0; ks < 2; ++ks)
    aq[ks] = *(const short8*)(g_Qp + ((size_t)nh * S_LEN + q0 + w * 16 + c) * HD + ks * 32 + g * 8);

  // staging: 512 threads cover 64 rows x 8 chunks (16B each)
  const int strow = tid >> 3, schunk = tid & 7;
  const int sdst = (schunk ^ (strow & 7)) * 8;
  const unsigned short* ksrc = g_Kp + ((size_t)nh * S_LEN + strow) * HD + schunk * 8;
  const unsigned short* vsrc = g_Vt + ((size_t)nh * HD + strow) * S_LEN + schunk * 8;
  const u64* mbase = g_Mb + ((size_t)n * 32) * S_LEN + q0 + w * 16 + 4 * g;

  float m4[4], l4[4];
  f32x4 O4[4];
#pragma unroll
  for (int r = 0; r < 4; ++r) { m4[r] = -1e29f; l4[r] = 0.f; }
#pragma unroll
  for (int dt = 0; dt < 4; ++dt) { O4[dt][0]=0.f; O4[dt][1]=0.f; O4[dt][2]=0.f; O4[dt][3]=0.f; }

  // prologue: tile 0
  short8 kst = *(const short8*)(ksrc);
  short8 vst = *(const short8*)(vsrc);
  u64x2 mA = *(const u64x2*)(mbase);
  u64x2 mB = *(const u64x2*)(mbase + 2);
  *(short8*)(&Kl[0][strow][sdst]) = kst;
  *(short8*)(&Vl[0][strow][sdst]) = vst;
  __syncthreads();

  for (int t = 0; t < 32; ++t) {
    const int cur = t & 1;
    u64x2 mAn, mBn;
    if (t < 31) {                       // prefetch t+1 (hidden under compute)
      kst = *(const short8*)(ksrc + (size_t)(t + 1) * 64 * HD);
      vst = *(const short8*)(vsrc + (t + 1) * 64);
      mAn = *(const u64x2*)(mbase + (size_t)(t + 1) * S_LEN);
      mBn = *(const u64x2*)(mbase + (size_t)(t + 1) * S_LEN + 2);
    }

    // S = Q K^T  (16 q-rows x 64 kv per wave)
    f32x4 sa[4];
#pragma unroll
    for (int ct = 0; ct < 4; ++ct) { sa[ct][0]=0.f; sa[ct][1]=0.f; sa[ct][2]=0.f; sa[ct][3]=0.f; }
#pragma unroll
    for (int ks = 0; ks < 2; ++ks)
#pragma unroll
      for (int ct = 0; ct < 4; ++ct) {
        short8 bk = *(const short8*)(&Kl[cur][ct * 16 + c][((g + 4 * ks) ^ (c & 7)) * 8]);
        sa[ct] = __builtin_amdgcn_mfma_f32_16x16x32_bf16(aq[ks], bk, sa[ct], 0, 0, 0);
      }

    // mask from prefetched bits (rows 4g+r, col bit = ct*16+c)
#pragma unroll
    for (int r = 0; r < 4; ++r) {
      u64 m64 = (r == 0) ? mA[0] : (r == 1) ? mA[1] : (r == 2) ? mB[0] : mB[1];
      unsigned lo = (unsigned)m64, hi = (unsigned)(m64 >> 32);
#pragma unroll
      for (int ct = 0; ct < 4; ++ct) {
        unsigned word = (ct & 2) ? hi : lo;
        int sh = (ct & 1) * 16 + c;
        sa[ct][r] = ((word >> sh) & 1u) ? sa[ct][r] : -1e30f;
      }
    }

    // online softmax per row (reduce over 16 lanes)
    float corr[4];
#pragma unroll
    for (int r = 0; r < 4; ++r) {
      float mx = fmaxf(fmaxf(sa[0][r], sa[1][r]), fmaxf(sa[2][r], sa[3][r]));
      mx = fmaxf(mx, __shfl_xor(mx, 1));
      mx = fmaxf(mx, __shfl_xor(mx, 2));
      mx = fmaxf(mx, __shfl_xor(mx, 4));
      mx = fmaxf(mx, __shfl_xor(mx, 8));
      float mn = fmaxf(m4[r], mx);
      corr[r] = __expf(m4[r] - mn);
      m4[r] = mn;
      float ps = 0.f;
#pragma unroll
      for (int ct = 0; ct < 4; ++ct) {
        float p = __expf(sa[ct][r] - mn);
        sa[ct][r] = p;
        ps += p;
      }
      ps += __shfl_xor(ps, 1); ps += __shfl_xor(ps, 2);
      ps += __shfl_xor(ps, 4); ps += __shfl_xor(ps, 8);
      l4[r] = l4[r] * corr[r] + ps;
    }

    // P -> wave-private swizzled LDS
#pragma unroll
    for (int ct = 0; ct < 4; ++ct)
#pragma unroll
      for (int r = 0; r < 4; ++r) {
        int prow = 4 * g + r, col = ct * 16 + c;
        Pl[w][prow][(((col >> 3) ^ (prow & 7)) << 3) | (col & 7)] = f2bf(sa[ct][r]);
      }

    // rescale O
#pragma unroll
    for (int dt = 0; dt < 4; ++dt)
#pragma unroll
      for (int r = 0; r < 4; ++r)
        O4[dt][r] *= corr[r];

    // O += P V
#pragma unroll
    for (int ks = 0; ks < 2; ++ks) {
      short8 pa = *(const short8*)(&Pl[w][c][((g + 4 * ks) ^ (c & 7)) * 8]);
#pragma unroll
      for (int dt = 0; dt < 4; ++dt) {
        short8 bv = *(const short8*)(&Vl[cur][dt * 16 + c][((g + 4 * ks) ^ (c & 7)) * 8]);
        O4[dt] = __builtin_amdgcn_mfma_f32_16x16x32_bf16(pa, bv, O4[dt], 0, 0, 0);
      }
    }

    __syncthreads();
    if (t < 31) {
      *(short8*)(&Kl[cur ^ 1][strow][sdst]) = kst;
      *(short8*)(&Vl[cur ^ 1][strow][sdst]) = vst;
      mA = mAn; mB = mBn;
    }
    __syncthreads();
  }

  // epilogue
#pragma unroll
  for (int r = 0; r < 4; ++r) {
    float inv = l4[r] > 0.f ? 1.f / l4[r] : 0.f;
    int qr = q0 + w * 16 + 4 * g + r;
#pragma unroll
    for (int dt = 0; dt < 4; ++dt)
      g_AO[((size_t)n * S_LEN + qr) * EMB + h * HD + dt * 16 + c] = f2bf(O4[dt][r] * inv);
  }
}

// ---------------- k3: output projection (8192x512x512) + bias ------------
// 64x64 tile per 256-thread block -> 1024 blocks (4/CU)
__global__ __launch_bounds__(256) void k3_oproj(const float* __restrict__ bo,
                                                float* __restrict__ out) {
  const int tid = threadIdx.x;
  const int w = tid >> 6, lane = tid & 63, g = lane >> 4, c = lane & 15;
  const int m0 = blockIdx.x * 64;
  const int n0 = blockIdx.y * 64;

  f32x4 acc[4];
#pragma unroll
  for (int ct = 0; ct < 4; ++ct) { acc[ct][0]=0.f; acc[ct][1]=0.f; acc[ct][2]=0.f; acc[ct][3]=0.f; }

  for (int ks = 0; ks < 16; ++ks) {
    short8 a = *(const short8*)(g_AO + ((size_t)(m0 + w * 16 + c)) * EMB + ks * 32 + g * 8);
#pragma unroll
    for (int ct = 0; ct < 4; ++ct) {
      short8 b = *(const short8*)(g_Wob + (size_t)(n0 + ct * 16 + c) * EMB + ks * 32 + g * 8);
      acc[ct] = __builtin_amdgcn_mfma_f32_16x16x32_bf16(a, b, acc[ct], 0, 0, 0);
    }
  }

#pragma unroll
  for (int ct = 0; ct < 4; ++ct) {
    int col = n0 + ct * 16 + c;
    float bias = bo[col];
#pragma unroll
    for (int r = 0; r < 4; ++r) {
      int row = m0 + w * 16 + 4 * g + r;
      out[(size_t)row * EMB + col] = acc[ct][r] + bias;
    }
  }
}

extern "C" void kernel_launch(void* const* d_in, const int* in_sizes, int n_in,
                              void* d_out, int out_size, void* d_ws, size_t ws_size,
                              hipStream_t stream) {
  const float* value = (const float*)d_in[0];
  const float* key   = (const float*)d_in[1];
  const float* query = (const float*)d_in[2];
  const int*   mask  = (const int*)d_in[3];
  const float* Wq    = (const float*)d_in[4];
  const float* Wk    = (const float*)d_in[5];
  const float* Wv    = (const float*)d_in[6];
  const float* Wo    = (const float*)d_in[7];
  const float* bo    = (const float*)d_in[8];
  float* out = (float*)d_out;

  k0_wconv<<<1072, 256, 0, stream>>>(Wq, Wk, Wv, Wo);
  k0b_mask<<<65536, 256, 0, stream>>>(mask);
  k1_proj<<<dim3(32, 32, 3), 256, 0, stream>>>(query, key, value);
  k2_attn<<<dim3(16, 32), 512, 0, stream>>>();
  k3_oproj<<<dim3(128, 8), 256, 0, stream>>>(bo, out);
}

// Round 7
// 273.390 us; speedup vs baseline: 1.5169x; 1.1936x over previous
//
#include <hip/hip_runtime.h>

typedef short short8 __attribute__((ext_vector_type(8)));
typedef float f32x4 __attribute__((ext_vector_type(4)));
typedef unsigned short ushort4v __attribute__((ext_vector_type(4)));
typedef unsigned long long u64;
typedef u64 u64x2 __attribute__((ext_vector_type(2)));

#define N_B   4
#define S_LEN 2048
#define EMB   512
#define HD    64
#define NHB   32                      // N_B * HEADS
// 1/sqrt(512) * log2(e): scores pre-scaled so p = exp2(s) (native v_exp_f32)
#define QSCALE 0.063758714f

// native 2^x (v_exp_f32)
#define EXP2F(x) __builtin_amdgcn_exp2f(x)

// static device scratch; fully rewritten every call
__device__ unsigned short g_Wqb[64*64];
__device__ unsigned short g_Wkb[64*64];
__device__ unsigned short g_Wvb[64*64];
__device__ unsigned short g_Wob[512*512];
__device__ unsigned short g_Qp[NHB*S_LEN*HD];   // [nh][s][d] (pre-scaled)
__device__ unsigned short g_Kp[NHB*S_LEN*HD];   // [nh][s][d]
__device__ unsigned short g_Vt[NHB*HD*S_LEN];   // [nh][d][s]
__device__ unsigned short g_AO[N_B*S_LEN*EMB];  // attention output, bf16
__device__ u64            g_Mb[N_B*32*S_LEN];   // packed mask bits [n][t][q]

__device__ __forceinline__ unsigned short f2bf(float f) {
  unsigned u = __float_as_uint(f);
  u = u + 0x7fffu + ((u >> 16) & 1u);   // RNE
  return (unsigned short)(u >> 16);
}

__device__ __forceinline__ unsigned cvt_pk_bf16(float a, float b) {
  unsigned r;
  asm("v_cvt_pk_bf16_f32 %0, %1, %2" : "=v"(r) : "v"(a), "v"(b));
  return r;   // low16 = bf16(a), high16 = bf16(b)
}

// ---------------- k0: weight f32 -> bf16 (Wq pre-scaled) ----------------
__global__ __launch_bounds__(256) void k0_wconv(const float* __restrict__ Wq,
                                                const float* __restrict__ Wk,
                                                const float* __restrict__ Wv,
                                                const float* __restrict__ Wo) {
  int idx = blockIdx.x * 256 + threadIdx.x;          // 274432 total
  if (idx < 4096)        g_Wqb[idx]         = f2bf(Wq[idx] * QSCALE);
  else if (idx < 8192)   g_Wkb[idx - 4096]  = f2bf(Wk[idx - 4096]);
  else if (idx < 12288)  g_Wvb[idx - 8192]  = f2bf(Wv[idx - 8192]);
  else                   g_Wob[idx - 12288] = f2bf(Wo[idx - 12288]);
}

// ---------------- k0b: pack mask -> bits; fat blocks (2048 WGs) ----------
// wave handles one (n,q): 32 ballot rounds over t, coalesced 256B reads
__global__ __launch_bounds__(256) void k0b_mask(const int* __restrict__ mask) {
  int wid = blockIdx.x * 4 + (threadIdx.x >> 6);      // 8192 waves = (n,q)
  int lane = threadIdx.x & 63;
  int n = wid >> 11, q = wid & 2047;
  const int* base = mask + ((size_t)(n * 2048 + q) << 11);
  u64* dst = g_Mb + (size_t)n * 32 * S_LEN + q;
#pragma unroll 4
  for (int j = 0; j < 32; ++j) {
    int mk = base[j * 64 + lane];
    u64 bits = __ballot(mk != 0);
    if (lane == 0) dst[(size_t)j * S_LEN] = bits;
  }
}

// ---------------- k1: QKV projections, swapped operands (C^T) -----------
// C^T[e][s]: A = W rows(e), B = X cols(s). Q/K: packed 8B stores.
// V: LDS transpose -> coalesced 16B stores into [d][s].
__global__ __launch_bounds__(256) void k1_proj(const float* __restrict__ q_in,
                                               const float* __restrict__ k_in,
                                               const float* __restrict__ v_in) {
  __shared__ unsigned short VtL[64][72];
  const int tid = threadIdx.x;
  const int w = tid >> 6, lane = tid & 63, g = lane >> 4, c = lane & 15;
  const int s0 = blockIdx.x * 64;
  const int nh = blockIdx.y, n = nh >> 3, h = nh & 7;
  const int which = blockIdx.z;                       // 0=q 1=k 2=v
  const float* src = which == 0 ? q_in : (which == 1 ? k_in : v_in);
  const unsigned short* Wb = which == 0 ? g_Wqb : (which == 1 ? g_Wkb : g_Wvb);

  // B fragments: X rows (col = s), f32 -> bf16
  short8 xb[2];
  const int srow = s0 + w * 16 + c;
#pragma unroll
  for (int ks = 0; ks < 2; ++ks) {
    const float* ap = src + ((size_t)n * S_LEN + srow) * EMB + h * HD + ks * 32 + g * 8;
    f32x4 x0 = *(const f32x4*)ap;
    f32x4 x1 = *(const f32x4*)(ap + 4);
    short8 tt;
    tt[0] = (short)f2bf(x0[0]); tt[1] = (short)f2bf(x0[1]);
    tt[2] = (short)f2bf(x0[2]); tt[3] = (short)f2bf(x0[3]);
    tt[4] = (short)f2bf(x1[0]); tt[5] = (short)f2bf(x1[1]);
    tt[6] = (short)f2bf(x1[2]); tt[7] = (short)f2bf(x1[3]);
    xb[ks] = tt;
  }

  f32x4 acc[4];
#pragma unroll
  for (int dt = 0; dt < 4; ++dt) { acc[dt][0]=0.f; acc[dt][1]=0.f; acc[dt][2]=0.f; acc[dt][3]=0.f; }

#pragma unroll
  for (int ks = 0; ks < 2; ++ks)
#pragma unroll
    for (int dt = 0; dt < 4; ++dt) {
      short8 a = *(const short8*)(Wb + (dt * 16 + c) * HD + ks * 32 + g * 8);
      acc[dt] = __builtin_amdgcn_mfma_f32_16x16x32_bf16(a, xb[ks], acc[dt], 0, 0, 0);
    }

  // acc[dt]: e = dt*16 + 4g + r, s = srow
  if (which < 2) {
    unsigned short* dst = which == 0 ? g_Qp : g_Kp;
#pragma unroll
    for (int dt = 0; dt < 4; ++dt) {
      ushort4v u;
      u[0] = f2bf(acc[dt][0]); u[1] = f2bf(acc[dt][1]);
      u[2] = f2bf(acc[dt][2]); u[3] = f2bf(acc[dt][3]);
      *(ushort4v*)(dst + ((size_t)nh * S_LEN + srow) * HD + dt * 16 + 4 * g) = u;
    }
  } else {
    // transpose tile in LDS, then coalesced 16B stores of Vt rows
#pragma unroll
    for (int dt = 0; dt < 4; ++dt)
#pragma unroll
      for (int r = 0; r < 4; ++r)
        VtL[dt * 16 + 4 * g + r][w * 16 + c] = f2bf(acc[dt][r]);
    __syncthreads();
#pragma unroll
    for (int rep = 0; rep < 2; ++rep) {
      int cid = tid + rep * 256;
      int row = cid >> 3, ch = cid & 7;
      short8 v = *(const short8*)(&VtL[row][ch * 8]);
      *(short8*)(g_Vt + ((size_t)nh * HD + row) * S_LEN + s0 + ch * 8) = v;
    }
  }
}

// ---------------- k2: flash attention, no-max softmax --------------------
// 8 waves x 16 q-rows = 128 q/block; dbuf swizzled LDS, ONE barrier/tile.
// Row-sums via 16 all-ones V rows (dt=4 MFMA tile) -> O5; out = O4/O5.
__global__ __launch_bounds__(512) void k2_attn() {
  __shared__ unsigned short Kl[2][64][64];   // [buf][kv][d], chunk^=(row&7)
  __shared__ unsigned short Vl[2][80][64];   // [buf][d][kv]; rows 64..79 = 1.0
  __shared__ unsigned short Pl[8][16][64];   // per-wave P [q][kv], swizzled
  const int tid = threadIdx.x;
  const int w = tid >> 6, lane = tid & 63, g = lane >> 4, c = lane & 15;
  const int q0 = blockIdx.x * 128;
  const int nh = blockIdx.y, n = nh >> 3;

  // Q fragments (16 rows per wave)
  short8 aq[2];
#pragma unroll
  for (int ks = 0; ks < 2; ++ks)
    aq[ks] = *(const short8*)(g_Qp + ((size_t)nh * S_LEN + q0 + w * 16 + c) * HD + ks * 32 + g * 8);

  // staging: 512 threads cover 64 rows x 8 chunks (16B each)
  const int strow = tid >> 3, schunk = tid & 7;
  const int sdst = (schunk ^ (strow & 7)) * 8;
  const unsigned short* ksrc = g_Kp + ((size_t)nh * S_LEN + strow) * HD + schunk * 8;
  const unsigned short* vsrc = g_Vt + ((size_t)nh * HD + strow) * S_LEN + schunk * 8;
  const u64* mbase = g_Mb + ((size_t)n * 32) * S_LEN + q0 + w * 16 + 4 * g;

  // ones rows (both buffers): [2][16][64] u16 = 2048; 512 thr x 4
  {
    int flat = tid * 4;
    int b = flat >> 10, rem = flat & 1023, rr = rem >> 6, cc = rem & 63;
    ushort4v ones4 = {0x3f80, 0x3f80, 0x3f80, 0x3f80};
    *(ushort4v*)(&Vl[b][64 + rr][cc]) = ones4;
  }

  f32x4 O4[4], O5;
#pragma unroll
  for (int dt = 0; dt < 4; ++dt) { O4[dt][0]=0.f; O4[dt][1]=0.f; O4[dt][2]=0.f; O4[dt][3]=0.f; }
  O5[0]=0.f; O5[1]=0.f; O5[2]=0.f; O5[3]=0.f;

  // prologue: tile 0
  short8 kst = *(const short8*)(ksrc);
  short8 vst = *(const short8*)(vsrc);
  u64x2 mA = *(const u64x2*)(mbase);
  u64x2 mB = *(const u64x2*)(mbase + 2);
  *(short8*)(&Kl[0][strow][sdst]) = kst;
  *(short8*)(&Vl[0][strow][sdst]) = vst;
  __syncthreads();

  for (int t = 0; t < 32; ++t) {
    const int cur = t & 1;
    u64x2 mAn, mBn;
    if (t < 31) {                       // prefetch t+1 (hidden under compute)
      kst = *(const short8*)(ksrc + (size_t)(t + 1) * 64 * HD);
      vst = *(const short8*)(vsrc + (t + 1) * 64);
      mAn = *(const u64x2*)(mbase + (size_t)(t + 1) * S_LEN);
      mBn = *(const u64x2*)(mbase + (size_t)(t + 1) * S_LEN + 2);
    }

    // S = Q K^T  (16 q-rows x 64 kv per wave), pre-scaled by QSCALE
    f32x4 sa[4];
#pragma unroll
    for (int ct = 0; ct < 4; ++ct) { sa[ct][0]=0.f; sa[ct][1]=0.f; sa[ct][2]=0.f; sa[ct][3]=0.f; }
#pragma unroll
    for (int ks = 0; ks < 2; ++ks)
#pragma unroll
      for (int ct = 0; ct < 4; ++ct) {
        short8 bk = *(const short8*)(&Kl[cur][ct * 16 + c][((g + 4 * ks) ^ (c & 7)) * 8]);
        sa[ct] = __builtin_amdgcn_mfma_f32_16x16x32_bf16(aq[ks], bk, sa[ct], 0, 0, 0);
      }

    // P = mask ? exp2(s) : 0   (no max subtraction: |s| <~ 1)
    // pack pairs with v_cvt_pk_bf16_f32, store to wave-private swizzled Pl
    unsigned lo0 = (unsigned)mA[0], hi0 = (unsigned)(mA[0] >> 32);
    unsigned lo1 = (unsigned)mA[1], hi1 = (unsigned)(mA[1] >> 32);
    unsigned lo2 = (unsigned)mB[0], hi2 = (unsigned)(mB[0] >> 32);
    unsigned lo3 = (unsigned)mB[1], hi3 = (unsigned)(mB[1] >> 32);
#pragma unroll
    for (int ct = 0; ct < 4; ++ct) {
      const int sh = (ct & 1) * 16 + c;
      float p0 = ((((ct & 2) ? hi0 : lo0) >> sh) & 1u) ? EXP2F(sa[ct][0]) : 0.f;
      float p1 = ((((ct & 2) ? hi1 : lo1) >> sh) & 1u) ? EXP2F(sa[ct][1]) : 0.f;
      float p2 = ((((ct & 2) ? hi2 : lo2) >> sh) & 1u) ? EXP2F(sa[ct][2]) : 0.f;
      float p3 = ((((ct & 2) ? hi3 : lo3) >> sh) & 1u) ? EXP2F(sa[ct][3]) : 0.f;
      unsigned pk01 = cvt_pk_bf16(p0, p1);
      unsigned pk23 = cvt_pk_bf16(p2, p3);
      const int col = ct * 16 + c;
      const int chs = ((col >> 3) << 3);          // chunk base (pre-XOR)
#pragma unroll
      for (int r = 0; r < 4; ++r) {
        int prow = 4 * g + r;
        unsigned pk = (r < 2) ? pk01 : pk23;
        unsigned short v = (r & 1) ? (unsigned short)(pk >> 16) : (unsigned short)pk;
        Pl[w][prow][(chs ^ ((prow & 7) << 3)) | (col & 7)] = v;
      }
    }

    // O += P V  (dt=0..3: output dims; dt=4: ones rows -> row-sum into O5)
#pragma unroll
    for (int ks = 0; ks < 2; ++ks) {
      short8 pa = *(const short8*)(&Pl[w][c][((g + 4 * ks) ^ (c & 7)) * 8]);
#pragma unroll
      for (int dt = 0; dt < 5; ++dt) {
        short8 bv = *(const short8*)(&Vl[cur][dt * 16 + c][((g + 4 * ks) ^ (c & 7)) * 8]);
        if (dt < 4)
          O4[dt] = __builtin_amdgcn_mfma_f32_16x16x32_bf16(pa, bv, O4[dt], 0, 0, 0);
        else
          O5 = __builtin_amdgcn_mfma_f32_16x16x32_bf16(pa, bv, O5, 0, 0, 0);
      }
    }

    if (t < 31) {
      *(short8*)(&Kl[cur ^ 1][strow][sdst]) = kst;
      *(short8*)(&Vl[cur ^ 1][strow][sdst]) = vst;
      mA = mAn; mB = mBn;
      __syncthreads();                   // single barrier per tile
    }
  }

  // epilogue: out = O4 / O5
  const int h = nh & 7;
#pragma unroll
  for (int r = 0; r < 4; ++r) {
    float inv = O5[r] > 0.f ? 1.f / O5[r] : 0.f;
    int qr = q0 + w * 16 + 4 * g + r;
#pragma unroll
    for (int dt = 0; dt < 4; ++dt)
      g_AO[((size_t)n * S_LEN + qr) * EMB + h * HD + dt * 16 + c] = f2bf(O4[dt][r] * inv);
  }
}

// ---------------- k3: output projection (8192x512x512) + bias ------------
__global__ __launch_bounds__(256) void k3_oproj(const float* __restrict__ bo,
                                                float* __restrict__ out) {
  const int tid = threadIdx.x;
  const int w = tid >> 6, lane = tid & 63, g = lane >> 4, c = lane & 15;
  const int m0 = blockIdx.x * 64;
  const int n0 = blockIdx.y * 64;

  f32x4 acc[4];
#pragma unroll
  for (int ct = 0; ct < 4; ++ct) { acc[ct][0]=0.f; acc[ct][1]=0.f; acc[ct][2]=0.f; acc[ct][3]=0.f; }

  for (int ks = 0; ks < 16; ++ks) {
    short8 a = *(const short8*)(g_AO + ((size_t)(m0 + w * 16 + c)) * EMB + ks * 32 + g * 8);
#pragma unroll
    for (int ct = 0; ct < 4; ++ct) {
      short8 b = *(const short8*)(g_Wob + (size_t)(n0 + ct * 16 + c) * EMB + ks * 32 + g * 8);
      acc[ct] = __builtin_amdgcn_mfma_f32_16x16x32_bf16(a, b, acc[ct], 0, 0, 0);
    }
  }

#pragma unroll
  for (int ct = 0; ct < 4; ++ct) {
    int col = n0 + ct * 16 + c;
    float bias = bo[col];
#pragma unroll
    for (int r = 0; r < 4; ++r) {
      int row = m0 + w * 16 + 4 * g + r;
      out[(size_t)row * EMB + col] = acc[ct][r] + bias;
    }
  }
}

extern "C" void kernel_launch(void* const* d_in, const int* in_sizes, int n_in,
                              void* d_out, int out_size, void* d_ws, size_t ws_size,
                              hipStream_t stream) {
  const float* value = (const float*)d_in[0];
  const float* key   = (const float*)d_in[1];
  const float* query = (const float*)d_in[2];
  const int*   mask  = (const int*)d_in[3];
  const float* Wq    = (const float*)d_in[4];
  const float* Wk    = (const float*)d_in[5];
  const float* Wv    = (const float*)d_in[6];
  const float* Wo    = (const float*)d_in[7];
  const float* bo    = (const float*)d_in[8];
  float* out = (float*)d_out;

  k0_wconv<<<1072, 256, 0, stream>>>(Wq, Wk, Wv, Wo);
  k0b_mask<<<2048, 256, 0, stream>>>(mask);
  k1_proj<<<dim3(32, 32, 3), 256, 0, stream>>>(query, key, value);
  k2_attn<<<dim3(16, 32), 512, 0, stream>>>();
  k3_oproj<<<dim3(128, 8), 256, 0, stream>>>(bo, out);
}